// Round 6
// baseline (138.352 us; speedup 1.0000x reference)
//
#include <hip/hip_runtime.h>
#include <hip/hip_bf16.h>

// Chamfer, B=4, N=M=8192 fp32 -> scalar. Round 6: MFMA split-bf16.
// d2[n][m] = |p|^2+|q|^2-2 p.q computed ONCE per pair (matrix is direction-symmetric)
// as a single K=13 bf16 contraction via hi/lo splitting:
//   A(p) = [-2xh,-2xh,-2xl, -2yh,-2yh,-2yl, -2zh,-2zh,-2zl, sh, sl, 1, 1, 0...]
//   B(q) = [ xh,  xl,  xh,   yh,  yl,  yh,   zh,  zl,  zh,  1,  1, sh', sl', 0...]
// bf16 products are exact in fp32; per-value error ~1e-4 -> worst-case sum error ~13 < 30.56.
// Row-mins (dist1) fold in registers + shuffle; col-mins (dist2) via per-tile LDS slots
// (each slot written exactly once -> no LDS atomics, no init) + block-end reduction.
// mfma_f32_16x16x32_bf16 layouts (HW-verified per guide): A[m=lane&15][k=(lane>>4)*8+j],
// C/D[row=(lane>>4)*4+reg][col=lane&15]. Transpose confusion is benign: output sums both axes.

#define NPTS 8192
#define SETPTS 32768           // 4 * 8192
#define MCHUNK 512             // cols per block
#define COLPAD 17              // LDS stride (conflict-free)

typedef short bf16x8 __attribute__((ext_vector_type(8)));
typedef float f32x4 __attribute__((ext_vector_type(4)));

__device__ inline unsigned short f2bf(float f) {  // RNE float->bf16
  unsigned int u = __float_as_uint(f);
  return (unsigned short)((u + 0x7FFFu + ((u >> 16) & 1u)) >> 16);
}
__device__ inline float bf2f(unsigned short h) { return __uint_as_float(((unsigned int)h) << 16); }
__device__ inline unsigned int pk(unsigned short lo, unsigned short hi) {
  return (unsigned int)lo | ((unsigned int)hi << 16);
}

__global__ __launch_bounds__(256) void chamfer_prep_kernel(
    const float* __restrict__ p1, const float* __restrict__ p2,
    uint4* __restrict__ preA4, uint4* __restrict__ preB4, unsigned int* __restrict__ wmin) {
  const int i = blockIdx.x * 256 + threadIdx.x;  // 0..32767 (point index, both sets)
  const unsigned short ONE = 0x3F80;

  {  // A-role: set 1 (rows / dist1)
    const float x = p1[3 * i], y = p1[3 * i + 1], z = p1[3 * i + 2];
    const unsigned short xh = f2bf(x), yh = f2bf(y), zh = f2bf(z);
    const unsigned short xl = f2bf(x - bf2f(xh)), yl = f2bf(y - bf2f(yh)), zl = f2bf(z - bf2f(zh));
    const float s = fmaf(x, x, fmaf(y, y, z * z));
    const unsigned short sh = f2bf(s), sl = f2bf(s - bf2f(sh));
    const unsigned short nxh = f2bf(-2.f * bf2f(xh)), nxl = f2bf(-2.f * bf2f(xl));
    const unsigned short nyh = f2bf(-2.f * bf2f(yh)), nyl = f2bf(-2.f * bf2f(yl));
    const unsigned short nzh = f2bf(-2.f * bf2f(zh)), nzl = f2bf(-2.f * bf2f(zl));
    preA4[i * 4 + 0] = make_uint4(pk(nxh, nxh), pk(nxl, nyh), pk(nyh, nyl), pk(nzh, nzh));
    preA4[i * 4 + 1] = make_uint4(pk(nzl, sh), pk(sl, ONE), pk(ONE, 0), 0u);
    preA4[i * 4 + 2] = make_uint4(0u, 0u, 0u, 0u);
    preA4[i * 4 + 3] = make_uint4(0u, 0u, 0u, 0u);
  }
  {  // B-role: set 2 (cols / dist2)
    const float x = p2[3 * i], y = p2[3 * i + 1], z = p2[3 * i + 2];
    const unsigned short xh = f2bf(x), yh = f2bf(y), zh = f2bf(z);
    const unsigned short xl = f2bf(x - bf2f(xh)), yl = f2bf(y - bf2f(yh)), zl = f2bf(z - bf2f(zh));
    const float s = fmaf(x, x, fmaf(y, y, z * z));
    const unsigned short sh = f2bf(s), sl = f2bf(s - bf2f(sh));
    preB4[i * 4 + 0] = make_uint4(pk(xh, xl), pk(xh, yh), pk(yl, yh), pk(zh, zl));
    preB4[i * 4 + 1] = make_uint4(pk(zh, ONE), pk(ONE, sh), pk(sl, 0), 0u);
    preB4[i * 4 + 2] = make_uint4(0u, 0u, 0u, 0u);
    preB4[i * 4 + 3] = make_uint4(0u, 0u, 0u, 0u);
  }
  wmin[i] = 0xFFFFFFFFu;           // dist1 mins (+inf, uint-ordered)
  wmin[SETPTS + i] = 0xFFFFFFFFu;  // dist2 mins
}

__global__ __launch_bounds__(256) void chamfer_mfma_kernel(
    const char* __restrict__ preA, const char* __restrict__ preB,
    unsigned int* __restrict__ wmin1, unsigned int* __restrict__ wmin2) {
  const int mchunkI = blockIdx.x;  // 0..15  (512 cols each)
  const int nblockI = blockIdx.y;  // 0..127 (64 rows each)
  const int b = blockIdx.z;        // batch
  const int t = threadIdx.x;
  const int w = t >> 6;            // wave 0..3
  const int lane = t & 63;
  const int quad = lane >> 4;
  const int c15 = lane & 15;

  const int nbase = nblockI * 64 + w * 16;     // this wave's 16 rows
  const int mbase = mchunkI * MCHUNK;

  // A fragment: lane holds A[m=c15][k=quad*8 + 0..7] -> 16B at point*64 + quad*16
  const bf16x8 afrag = *(const bf16x8*)(preA + ((size_t)(b * NPTS + nbase + c15) * 64 + quad * 16));
  // B fragment base for this lane (advances 1024B per 16-col tile)
  const char* pB = preB + ((size_t)(b * NPTS + mbase + c15) * 64 + quad * 16);

  // col-candidate LDS: slot (col, quad, wave), written exactly once each -> no init/atomics
  __shared__ float colc[MCHUNK * COLPAD];
  float* myslot = &colc[c15 * COLPAD + quad * 4 + w];

  const f32x4 zero4 = {0.f, 0.f, 0.f, 0.f};
  float r0 = INFINITY, r1 = INFINITY, r2 = INFINITY, r3 = INFINITY;

#pragma unroll 8
  for (int mt = 0; mt < MCHUNK / 16; mt += 2) {
    const bf16x8 b0 = *(const bf16x8*)(pB + (size_t)mt * 1024);
    const bf16x8 b1 = *(const bf16x8*)(pB + (size_t)mt * 1024 + 1024);
    const f32x4 D0 = __builtin_amdgcn_mfma_f32_16x16x32_bf16(afrag, b0, zero4, 0, 0, 0);
    const f32x4 D1 = __builtin_amdgcn_mfma_f32_16x16x32_bf16(afrag, b1, zero4, 0, 0, 0);
    // col candidates: min over this lane's 4 rows (one per tile)
    myslot[(mt + 0) * 16 * COLPAD] = fminf(fminf(D0[0], D0[1]), fminf(D0[2], D0[3]));
    myslot[(mt + 1) * 16 * COLPAD] = fminf(fminf(D1[0], D1[1]), fminf(D1[2], D1[3]));
    // row folds (min3 pairs across the two tiles)
    r0 = fminf(fminf(r0, D0[0]), D1[0]);
    r1 = fminf(fminf(r1, D0[1]), D1[1]);
    r2 = fminf(fminf(r2, D0[2]), D1[2]);
    r3 = fminf(fminf(r3, D0[3]), D1[3]);
  }

  // row-min: reduce across the 16 lanes (cols) of each quad
#pragma unroll
  for (int off = 1; off < 16; off <<= 1) {
    r0 = fminf(r0, __shfl_xor(r0, off, 64));
    r1 = fminf(r1, __shfl_xor(r1, off, 64));
    r2 = fminf(r2, __shfl_xor(r2, off, 64));
    r3 = fminf(r3, __shfl_xor(r3, off, 64));
  }
  if (c15 == 0) {
    unsigned int* wr = wmin1 + (size_t)b * NPTS + nbase + quad * 4;
    atomicMin(&wr[0], __float_as_uint(fmaxf(r0, 0.f)));
    atomicMin(&wr[1], __float_as_uint(fmaxf(r1, 0.f)));
    atomicMin(&wr[2], __float_as_uint(fmaxf(r2, 0.f)));
    atomicMin(&wr[3], __float_as_uint(fmaxf(r3, 0.f)));
  }

  __syncthreads();
  // col-min: each thread reduces 2 cols over the 16 (quad,wave) slots
  for (int c = t; c < MCHUNK; c += 256) {
    const float* s = &colc[c * COLPAD];
    float v = s[0];
#pragma unroll
    for (int k = 1; k < 16; ++k) v = fminf(v, s[k]);
    atomicMin(&wmin2[(size_t)b * NPTS + mbase + c], __float_as_uint(fmaxf(v, 0.f)));
  }
}

__global__ __launch_bounds__(1024) void chamfer_reduce_kernel(
    const float4* __restrict__ wmin4, float* __restrict__ out) {
  // 65536 floats = 16384 float4; one block of 1024 threads, 16 float4 each
  float s = 0.f;
  const int t = threadIdx.x;
#pragma unroll
  for (int k = 0; k < 16; ++k) {
    const float4 v = wmin4[k * 1024 + t];
    s += (v.x + v.y) + (v.z + v.w);
  }
#pragma unroll
  for (int off = 32; off > 0; off >>= 1) s += __shfl_down(s, off, 64);
  __shared__ float wsum[16];
  const int lane = t & 63, wid = t >> 6;
  if (lane == 0) wsum[wid] = s;
  __syncthreads();
  if (t == 0) {
    float tot = 0.f;
#pragma unroll
    for (int w2 = 0; w2 < 16; ++w2) tot += wsum[w2];
    out[0] = tot;
  }
}

extern "C" void kernel_launch(void* const* d_in, const int* in_sizes, int n_in,
                              void* d_out, int out_size, void* d_ws, size_t ws_size,
                              hipStream_t stream) {
  const float* p1 = (const float*)d_in[0];
  const float* p2 = (const float*)d_in[1];
  float* out = (float*)d_out;
  char* ws = (char*)d_ws;
  uint4* preA4 = (uint4*)ws;                              // 2 MB
  uint4* preB4 = (uint4*)(ws + (1u << 21));               // 2 MB
  unsigned int* wmin = (unsigned int*)(ws + (1u << 22));  // 65536 u32 = 256 KB

  chamfer_prep_kernel<<<dim3(SETPTS / 256), dim3(256), 0, stream>>>(p1, p2, preA4, preB4, wmin);

  dim3 grid(NPTS / MCHUNK, NPTS / 64, 4);  // (16, 128, 4)
  chamfer_mfma_kernel<<<grid, dim3(256), 0, stream>>>((const char*)preA4, (const char*)preB4,
                                                      wmin, wmin + SETPTS);

  chamfer_reduce_kernel<<<dim3(1), dim3(1024), 0, stream>>>((const float4*)wmin, out);
}

// Round 8
// 125.604 us; speedup vs baseline: 1.1015x; 1.1015x over previous
//
#include <hip/hip_runtime.h>
#include <hip/hip_bf16.h>

// Chamfer, B=4, N=M=8192 fp32 -> scalar. Round 8: round-6 prep/reduce (validated absmax 0.0)
// + round-7 phase-2 MFMA main as a standalone dispatch (cooperative launch fails under graph
// capture -> reverted to 3 plain dispatches; non-main time is ~50us fixed regardless).
// Main: 8 A-frags/wave (128 rows) per prefetched B-tile pair -> 16 MFMA per 2 loads;
// col-mins via per-lane fold + shfl_xor(16/32) + [512][4] stride-5 LDS (conflict-free, 10 KB).

#define NPTS 8192
#define SETPTS 32768  // 4 * 8192
#define MCH 512       // cols per block
#define RCH 512       // rows per block

typedef short bf16x8 __attribute__((ext_vector_type(8)));
typedef float f32x4 __attribute__((ext_vector_type(4)));

__device__ inline unsigned short f2bf(float f) {  // RNE float->bf16
  unsigned int u = __float_as_uint(f);
  return (unsigned short)((u + 0x7FFFu + ((u >> 16) & 1u)) >> 16);
}
__device__ inline float bf2f(unsigned short h) { return __uint_as_float(((unsigned int)h) << 16); }
__device__ inline unsigned int pk(unsigned short lo, unsigned short hi) {
  return (unsigned int)lo | ((unsigned int)hi << 16);
}

__global__ __launch_bounds__(256) void chamfer_prep_kernel(
    const float* __restrict__ p1, const float* __restrict__ p2,
    uint4* __restrict__ preA4, uint4* __restrict__ preB4, unsigned int* __restrict__ wmin) {
  const int i = blockIdx.x * 256 + threadIdx.x;  // 0..32767 (point index, both sets)
  const unsigned short ONE = 0x3F80;

  {  // A-role: set 1 (rows / dist1). K=13 split-bf16 embedding (validated round 6).
    const float x = p1[3 * i], y = p1[3 * i + 1], z = p1[3 * i + 2];
    const unsigned short xh = f2bf(x), yh = f2bf(y), zh = f2bf(z);
    const unsigned short xl = f2bf(x - bf2f(xh)), yl = f2bf(y - bf2f(yh)), zl = f2bf(z - bf2f(zh));
    const float s = fmaf(x, x, fmaf(y, y, z * z));
    const unsigned short sh = f2bf(s), sl = f2bf(s - bf2f(sh));
    const unsigned short nxh = f2bf(-2.f * bf2f(xh)), nxl = f2bf(-2.f * bf2f(xl));
    const unsigned short nyh = f2bf(-2.f * bf2f(yh)), nyl = f2bf(-2.f * bf2f(yl));
    const unsigned short nzh = f2bf(-2.f * bf2f(zh)), nzl = f2bf(-2.f * bf2f(zl));
    preA4[i * 4 + 0] = make_uint4(pk(nxh, nxh), pk(nxl, nyh), pk(nyh, nyl), pk(nzh, nzh));
    preA4[i * 4 + 1] = make_uint4(pk(nzl, sh), pk(sl, ONE), pk(ONE, 0), 0u);
    preA4[i * 4 + 2] = make_uint4(0u, 0u, 0u, 0u);
    preA4[i * 4 + 3] = make_uint4(0u, 0u, 0u, 0u);
  }
  {  // B-role: set 2 (cols / dist2)
    const float x = p2[3 * i], y = p2[3 * i + 1], z = p2[3 * i + 2];
    const unsigned short xh = f2bf(x), yh = f2bf(y), zh = f2bf(z);
    const unsigned short xl = f2bf(x - bf2f(xh)), yl = f2bf(y - bf2f(yh)), zl = f2bf(z - bf2f(zh));
    const float s = fmaf(x, x, fmaf(y, y, z * z));
    const unsigned short sh = f2bf(s), sl = f2bf(s - bf2f(sh));
    preB4[i * 4 + 0] = make_uint4(pk(xh, xl), pk(xh, yh), pk(yl, yh), pk(zh, zl));
    preB4[i * 4 + 1] = make_uint4(pk(zh, ONE), pk(ONE, sh), pk(sl, 0), 0u);
    preB4[i * 4 + 2] = make_uint4(0u, 0u, 0u, 0u);
    preB4[i * 4 + 3] = make_uint4(0u, 0u, 0u, 0u);
  }
  wmin[i] = 0xFFFFFFFFu;           // dist1 mins (+inf, uint-ordered)
  wmin[SETPTS + i] = 0xFFFFFFFFu;  // dist2 mins
}

__global__ __launch_bounds__(256, 4) void chamfer_mfma_kernel(
    const char* __restrict__ preA, const char* __restrict__ preB,
    unsigned int* __restrict__ wmin1, unsigned int* __restrict__ wmin2) {
  const int bid = blockIdx.x;      // 0..1023
  const int b = bid >> 8;          // batch 0..3
  const int rb = (bid >> 4) & 15;  // row block (512 rows)
  const int cc = bid & 15;         // col chunk (512 cols)
  const int t = threadIdx.x;
  const int w = t >> 6, lane = t & 63, quad = lane >> 4, c15 = lane & 15;
  const int rowbase = rb * RCH + w * 128;  // this wave's 128 rows
  const int colbase = cc * MCH;

  // A fragments: lane holds A[m=c15][k=quad*8+j] -> 16B at point*64 + quad*16
  bf16x8 afr[8];
#pragma unroll
  for (int f = 0; f < 8; ++f)
    afr[f] = *(const bf16x8*)(preA + ((size_t)(b * NPTS + rowbase + f * 16 + c15) * 64 + quad * 16));

  f32x4 racc[8];
#pragma unroll
  for (int f = 0; f < 8; ++f) racc[f] = (f32x4){INFINITY, INFINITY, INFINITY, INFINITY};

  __shared__ float colc[MCH * 5];  // slot [col][wave], stride 5 (conflict-free, 10 KB)

  const char* pB = preB + ((size_t)(b * NPTS + colbase + c15) * 64 + quad * 16);
  bf16x8 nb0 = *(const bf16x8*)(pB);
  bf16x8 nb1 = *(const bf16x8*)(pB + 1024);
  const f32x4 z4 = {0.f, 0.f, 0.f, 0.f};

  for (int it = 0; it < 16; ++it) {
    const bf16x8 b0 = nb0, b1 = nb1;
    if (it < 15) {  // prefetch next two 16-col tiles
      nb0 = *(const bf16x8*)(pB + (size_t)(2 * it + 2) * 1024);
      nb1 = *(const bf16x8*)(pB + (size_t)(2 * it + 3) * 1024);
    }
    float cnd0 = INFINITY, cnd1 = INFINITY;
#pragma unroll
    for (int f = 0; f < 8; ++f) {
      const f32x4 D0 = __builtin_amdgcn_mfma_f32_16x16x32_bf16(afr[f], b0, z4, 0, 0, 0);
      const f32x4 D1 = __builtin_amdgcn_mfma_f32_16x16x32_bf16(afr[f], b1, z4, 0, 0, 0);
#pragma unroll
      for (int i = 0; i < 4; ++i)
        racc[f][i] = fminf(fminf(racc[f][i], D0[i]), D1[i]);  // v_min3
      cnd0 = fminf(cnd0, fminf(fminf(D0[0], D0[1]), fminf(D0[2], D0[3])));
      cnd1 = fminf(cnd1, fminf(fminf(D1[0], D1[1]), fminf(D1[2], D1[3])));
    }
    // combine the 4 quads' disjoint row-stripes -> col candidate over all 128 rows
    cnd0 = fminf(cnd0, __shfl_xor(cnd0, 16, 64));
    cnd0 = fminf(cnd0, __shfl_xor(cnd0, 32, 64));
    cnd1 = fminf(cnd1, __shfl_xor(cnd1, 16, 64));
    cnd1 = fminf(cnd1, __shfl_xor(cnd1, 32, 64));
    if (quad == 0) {  // 16 lanes, stride-5 dword addresses: conflict-free
      colc[(2 * it * 16 + c15) * 5 + w] = cnd0;
      colc[((2 * it + 1) * 16 + c15) * 5 + w] = cnd1;
    }
  }

  // row epilogue: D layout row=quad*4+i, col=c15 -> reduce across the 16 col-lanes
#pragma unroll
  for (int f = 0; f < 8; ++f)
#pragma unroll
    for (int i = 0; i < 4; ++i) {
      float v = racc[f][i];
      v = fminf(v, __shfl_xor(v, 1, 64));
      v = fminf(v, __shfl_xor(v, 2, 64));
      v = fminf(v, __shfl_xor(v, 4, 64));
      v = fminf(v, __shfl_xor(v, 8, 64));
      racc[f][i] = v;
    }
  if (c15 == 0) {
    unsigned int* wr = wmin1 + (size_t)b * NPTS + rowbase;
#pragma unroll
    for (int f = 0; f < 8; ++f)
#pragma unroll
      for (int i = 0; i < 4; ++i)
        atomicMin(&wr[f * 16 + quad * 4 + i], __float_as_uint(fmaxf(racc[f][i], 0.f)));
  }
  __syncthreads();
  // col epilogue: 2 cols per thread, fold the 4 wave-slots
  for (int c = t; c < MCH; c += 256) {
    const float v = fminf(fminf(colc[c * 5 + 0], colc[c * 5 + 1]),
                          fminf(colc[c * 5 + 2], colc[c * 5 + 3]));
    atomicMin(&wmin2[(size_t)b * NPTS + colbase + c], __float_as_uint(fmaxf(v, 0.f)));
  }
}

__global__ __launch_bounds__(1024) void chamfer_reduce_kernel(
    const float4* __restrict__ wmin4, float* __restrict__ out) {
  // 65536 floats = 16384 float4; one block of 1024 threads, 16 float4 each
  float s = 0.f;
  const int t = threadIdx.x;
#pragma unroll
  for (int k = 0; k < 16; ++k) {
    const float4 v = wmin4[k * 1024 + t];
    s += (v.x + v.y) + (v.z + v.w);
  }
#pragma unroll
  for (int off = 32; off > 0; off >>= 1) s += __shfl_down(s, off, 64);
  __shared__ float wsum[16];
  const int lane = t & 63, wid = t >> 6;
  if (lane == 0) wsum[wid] = s;
  __syncthreads();
  if (t == 0) {
    float tot = 0.f;
#pragma unroll
    for (int w2 = 0; w2 < 16; ++w2) tot += wsum[w2];
    out[0] = tot;
  }
}

extern "C" void kernel_launch(void* const* d_in, const int* in_sizes, int n_in,
                              void* d_out, int out_size, void* d_ws, size_t ws_size,
                              hipStream_t stream) {
  const float* p1 = (const float*)d_in[0];
  const float* p2 = (const float*)d_in[1];
  float* out = (float*)d_out;
  char* ws = (char*)d_ws;
  uint4* preA4 = (uint4*)ws;                              // 2 MB
  uint4* preB4 = (uint4*)(ws + (1u << 21));               // 2 MB
  unsigned int* wmin = (unsigned int*)(ws + (1u << 22));  // 65536 u32 = 256 KB

  chamfer_prep_kernel<<<dim3(SETPTS / 256), dim3(256), 0, stream>>>(p1, p2, preA4, preB4, wmin);

  chamfer_mfma_kernel<<<dim3(1024), dim3(256), 0, stream>>>((const char*)preA4,
                                                            (const char*)preB4, wmin,
                                                            wmin + SETPTS);

  chamfer_reduce_kernel<<<dim3(1), dim3(1024), 0, stream>>>((const float4*)wmin, out);
}